// Round 1
// 369.691 us; speedup vs baseline: 1.0404x; 1.0404x over previous
//
#include <hip/hip_runtime.h>

#define T_TOK 2048
#define DIM   2048
#define NEXP  8
#define FF    768
#define NGRP  16   // (expert, slot)
#define BK    64

typedef unsigned short u16;
typedef unsigned int   u32;
typedef __bf16 bf16x8 __attribute__((ext_vector_type(8)));
typedef float  f32x4  __attribute__((ext_vector_type(4)));
typedef u16    u16x4  __attribute__((ext_vector_type(4)));
typedef u16    u16x8  __attribute__((ext_vector_type(8)));

#define AS1 __attribute__((address_space(1)))
#define AS3 __attribute__((address_space(3)))

__device__ __forceinline__ u16 f2bf(float f) {
    union { u32 i; float f; } v; v.f = f;
    u32 r = v.i + 0x7FFF + ((v.i >> 16) & 1);   // round-to-nearest-even
    return (u16)(r >> 16);
}
__device__ __forceinline__ float bf2f(u16 u) {
    union { u32 i; float f; } v; v.i = ((u32)u) << 16; return v.f;
}

// async global->LDS, 16B per lane; LDS dest = wave-uniform base + lane*16
__device__ __forceinline__ void gload16(const u16* g, u16* l) {
    __builtin_amdgcn_global_load_lds((const AS1 u32*)g, (AS3 u32*)l, 16, 0, 0);
}

// ---------------- fp32 -> bf16 bulk convert (3 weight tensors) ----------------
__global__ void cvt3_kernel(const float* __restrict__ s0, u16* __restrict__ d0,
                            const float* __restrict__ s1, u16* __restrict__ d1,
                            const float* __restrict__ s2, u16* __restrict__ d2, int n4) {
    const float* s; u16* d;
    switch (blockIdx.y) {
        case 0: s = s0; d = d0; break;
        case 1: s = s1; d = d1; break;
        default: s = s2; d = d2; break;
    }
    int i = blockIdx.x * blockDim.x + threadIdx.x;
    int st = gridDim.x * blockDim.x;
    for (; i < n4; i += st) {
        f32x4 v = ((const f32x4*)s)[i];
        u16x4 o;
#pragma unroll
        for (int j = 0; j < 4; j++) o[j] = f2bf(v[j]);
        ((u16x4*)d)[i] = o;
    }
}

// ------- Router: scores, top-2, softmax, counts; also emits xb = bf16(x) -------
__global__ void router_kernel(const float* __restrict__ x, const float* __restrict__ wr,
                              int* cnt, int* rt_e, float* rt_p, u16* __restrict__ xb) {
    int wave = threadIdx.x >> 6, lane = threadIdx.x & 63;
    int t = blockIdx.x * 4 + wave;
    float xv[32];
#pragma unroll
    for (int i = 0; i < 32; i++) xv[i] = x[(size_t)t * DIM + i * 64 + lane];
#pragma unroll
    for (int i = 0; i < 32; i++) xb[(size_t)t * DIM + i * 64 + lane] = f2bf(xv[i]);
    float s[NEXP];
#pragma unroll
    for (int e = 0; e < NEXP; e++) {
        float acc = 0.f;
#pragma unroll
        for (int i = 0; i < 32; i++) acc += xv[i] * wr[(size_t)e * DIM + i * 64 + lane];
        for (int off = 32; off; off >>= 1) acc += __shfl_xor(acc, off);
        s[e] = acc;
    }
    if (lane == 0) {
        int bi = 0; float bv = s[0];
        for (int e = 1; e < NEXP; e++) if (s[e] > bv) { bv = s[e]; bi = e; }
        float sv = -1e30f; int si = 0;
        for (int e = 0; e < NEXP; e++) { if (e == bi) continue; if (s[e] > sv) { sv = s[e]; si = e; } }
        float p0 = 1.f / (1.f + __expf(sv - bv));
        float p1 = 1.f - p0;
        rt_e[t * 2 + 0] = bi; rt_e[t * 2 + 1] = si;
        rt_p[t * 2 + 0] = p0; rt_p[t * 2 + 1] = p1;
        atomicAdd(&cnt[bi * 2 + 0], 1);
        atomicAdd(&cnt[si * 2 + 1], 1);
    }
}

// ---------------- Scan (one wave): bases + 128-row tile worklist ----------------
__global__ void scan_kernel(const int* cnt, int* base, int* tile_g, int* tile_m0, int* ntiles) {
    int lane = threadIdx.x;
    int c = (lane < NGRP) ? cnt[lane] : 0;
    int nt_g = (c + 127) >> 7;
    int pre = 0, tpre = 0;
    for (int i = 0; i < NGRP; i++) {
        int ci = __shfl(c, i), ti = __shfl(nt_g, i);
        if (i < lane) { pre += ci; tpre += ti; }
    }
    if (lane < NGRP) {
        base[lane] = pre;
        for (int j = 0; j < nt_g; j++) { tile_g[tpre + j] = lane; tile_m0[tpre + j] = j * 128; }
        if (lane == NGRP - 1) *ntiles = tpre + nt_g;
    }
}

// ---------------- Assign: compact row -> (token, prob) ----------------
__global__ void assign_kernel(const int* rt_e, const float* rt_p, const int* base,
                              int* poscnt, int* rowtok, float* rowprob) {
    int t = blockIdx.x * blockDim.x + threadIdx.x;
    if (t >= T_TOK) return;
    for (int k = 0; k < 2; k++) {
        int g = rt_e[t * 2 + k] * 2 + k;
        int pos = atomicAdd(&poscnt[g], 1);
        int row = base[g] + pos;
        rowtok[row] = t;
        rowprob[row] = rt_p[t * 2 + k];
    }
}

// ---- Gate/Up GEMM + SiLU: 128 rows x 32 f (N=64: gate|up 16-col frags) ----
// BK=64, double-buffered LDS, one barrier per K-step, XOR chunk-swizzle
// (linear gload16 dest + inverse-swizzled global source + swizzled ds_read).
__launch_bounds__(256)
__global__ void gateup_kernel(const u16* __restrict__ xb, const u16* __restrict__ wgb,
                              const u16* __restrict__ wub,
                              const int* cnt, const int* base, const int* tile_g,
                              const int* tile_m0, const int* ntiles,
                              const int* rowtok, const float* rowprob,
                              u16* __restrict__ hidden) {
    int tile = blockIdx.x;
    if (tile >= *ntiles) return;
    int g = tile_g[tile], m0 = tile_m0[tile];
    int e = g >> 1;
    int f0 = blockIdx.y * 32;
    int cg = cnt[g], bg_ = base[g];

    __shared__ u16 As[2][128 * BK];   // 2 x 16 KB
    __shared__ u16 Bs[2][64 * BK];    // 2 x 8 KB
    __shared__ int   tks[128];
    __shared__ float ps[128];

    int tid = threadIdx.x;
    if (tid < 128) {
        int valid = (m0 + tid) < cg;
        tks[tid] = valid ? rowtok[bg_ + m0 + tid] : 0;
        ps[tid]  = valid ? rowprob[bg_ + m0 + tid] : 0.f;
    }
    __syncthreads();

    int wave = tid >> 6, lane = tid & 63;
    int quad = lane >> 4, l16 = lane & 15;
    int wr = wave >> 1, wc = wave & 1;

    // staging lane decomposition: 8 rows x 8 chunks of 16B per gload16 group
    int r8  = lane >> 3;                  // row within 8-row group
    int csw = ((lane & 7) ^ r8) * 8;      // inverse-swizzled global chunk (elements)

    // A: wave stages rows [wave*32, +32) in 4 groups of 8
    const u16* gA[4]; int lA[4];
#pragma unroll
    for (int gi = 0; gi < 4; gi++) {
        int row = wave * 32 + gi * 8 + r8;
        gA[gi] = xb + (size_t)tks[row] * DIM + csw;
        lA[gi] = (wave * 32 + gi * 8) * BK;
    }
    // B LDS row n: frag=(n>>4)&1 (0=gate,1=up), f=f0+(n>>5)*16+(n&15)
    // wave stages rows [wave*16, +16) in 2 groups of 8: frag=wave&1
    const u16* bsrc = (wave & 1) ? wub : wgb;
    const u16* gB[2]; int lB[2];
#pragma unroll
    for (int gi = 0; gi < 2; gi++) {
        int f = f0 + (wave >> 1) * 16 + gi * 8 + r8;
        gB[gi] = bsrc + ((size_t)e * FF + f) * DIM + csw;
        lB[gi] = (wave * 16 + gi * 8) * BK;
    }

    f32x4 acc[4][2] = {};

    // prologue: stage buffer 0 (kk = 0)
#pragma unroll
    for (int gi = 0; gi < 4; gi++) gload16(gA[gi], &As[0][0] + lA[gi]);
#pragma unroll
    for (int gi = 0; gi < 2; gi++) gload16(gB[gi], &Bs[0][0] + lB[gi]);
    __syncthreads();

    int sw0 = ((0 * 4 + quad) ^ (l16 & 7)) * 8;   // ks=0 swizzled chunk offset
    int sw1 = ((1 * 4 + quad) ^ (l16 & 7)) * 8;   // ks=1

#pragma unroll 2
    for (int kt = 0; kt < DIM / BK; kt++) {
        int cur = kt & 1;
        int kk = (kt + 1) * BK;
        if (kk < DIM) {
#pragma unroll
            for (int gi = 0; gi < 4; gi++) gload16(gA[gi] + kk, &As[cur ^ 1][0] + lA[gi]);
#pragma unroll
            for (int gi = 0; gi < 2; gi++) gload16(gB[gi] + kk, &Bs[cur ^ 1][0] + lB[gi]);
        }
#pragma unroll
        for (int ks = 0; ks < 2; ks++) {
            int sw = ks ? sw1 : sw0;
            bf16x8 a[4], b[2];
#pragma unroll
            for (int mi = 0; mi < 4; mi++)
                a[mi] = *(const bf16x8*)&As[cur][(wr * 64 + mi * 16 + l16) * BK + sw];
#pragma unroll
            for (int ni = 0; ni < 2; ni++)
                b[ni] = *(const bf16x8*)&Bs[cur][(wc * 32 + ni * 16 + l16) * BK + sw];
#pragma unroll
            for (int mi = 0; mi < 4; mi++)
#pragma unroll
                for (int ni = 0; ni < 2; ni++)
                    acc[mi][ni] = __builtin_amdgcn_mfma_f32_16x16x32_bf16(a[mi], b[ni], acc[mi][ni], 0, 0, 0);
        }
        __syncthreads();
    }

    // epilogue: gate = acc[mi][0], up = acc[mi][1]; f = f0 + wc*16 + l16
    int f = f0 + wc * 16 + l16;
#pragma unroll
    for (int mi = 0; mi < 4; mi++) {
#pragma unroll
        for (int r = 0; r < 4; r++) {
            int m = wr * 64 + mi * 16 + quad * 4 + r;
            if (m0 + m < cg) {
                float gv = acc[mi][0][r], uv = acc[mi][1][r];
                float h = (gv / (1.f + __expf(-gv))) * uv * ps[m];
                hidden[(size_t)(bg_ + m0 + m) * FF + f] = f2bf(h);
            }
        }
    }
}

// ---- Down GEMM: 128 rows x 64 d, BK=64, dbuf, swizzled, slot-scatter stores ----
__launch_bounds__(256)
__global__ void down_kernel(const u16* __restrict__ hid, const u16* __restrict__ wdb,
                            const int* cnt, const int* base, const int* tile_g,
                            const int* tile_m0, const int* ntiles, const int* rowtok,
                            u16* __restrict__ out0, u16* __restrict__ out1) {
    int tile = blockIdx.x;
    if (tile >= *ntiles) return;
    int g = tile_g[tile], m0 = tile_m0[tile];
    int e = g >> 1, slot = g & 1;
    int d0 = blockIdx.y * 64;
    int cg = cnt[g], bg_ = base[g];

    __shared__ u16 As[2][128 * BK];   // 2 x 16 KB
    __shared__ u16 Bs[2][64 * BK];    // 2 x 8 KB
    __shared__ int tks[128];

    int tid = threadIdx.x;
    if (tid < 128) tks[tid] = ((m0 + tid) < cg) ? rowtok[bg_ + m0 + tid] : 0;
    __syncthreads();

    int wave = tid >> 6, lane = tid & 63;
    int quad = lane >> 4, l16 = lane & 15;
    int wr = wave >> 1, wc = wave & 1;

    int r8  = lane >> 3;
    int csw = ((lane & 7) ^ r8) * 8;

    const u16* gA[4]; int lA[4];
#pragma unroll
    for (int gi = 0; gi < 4; gi++) {
        int row = wave * 32 + gi * 8 + r8;
        gA[gi] = hid + (size_t)(bg_ + m0 + row) * FF + csw;
        lA[gi] = (wave * 32 + gi * 8) * BK;
    }
    const u16* gB[2]; int lB[2];
#pragma unroll
    for (int gi = 0; gi < 2; gi++) {
        int n = wave * 16 + gi * 8 + r8;       // Bs row n <-> d = d0 + n
        gB[gi] = wdb + ((size_t)e * DIM + d0 + n) * FF + csw;
        lB[gi] = (wave * 16 + gi * 8) * BK;
    }

    f32x4 acc[4][2] = {};

#pragma unroll
    for (int gi = 0; gi < 4; gi++) gload16(gA[gi], &As[0][0] + lA[gi]);
#pragma unroll
    for (int gi = 0; gi < 2; gi++) gload16(gB[gi], &Bs[0][0] + lB[gi]);
    __syncthreads();

    int sw0 = ((0 * 4 + quad) ^ (l16 & 7)) * 8;
    int sw1 = ((1 * 4 + quad) ^ (l16 & 7)) * 8;

#pragma unroll 2
    for (int kt = 0; kt < FF / BK; kt++) {
        int cur = kt & 1;
        int kk = (kt + 1) * BK;
        if (kk < FF) {
#pragma unroll
            for (int gi = 0; gi < 4; gi++) gload16(gA[gi] + kk, &As[cur ^ 1][0] + lA[gi]);
#pragma unroll
            for (int gi = 0; gi < 2; gi++) gload16(gB[gi] + kk, &Bs[cur ^ 1][0] + lB[gi]);
        }
#pragma unroll
        for (int ks = 0; ks < 2; ks++) {
            int sw = ks ? sw1 : sw0;
            bf16x8 a[4], b[2];
#pragma unroll
            for (int mi = 0; mi < 4; mi++)
                a[mi] = *(const bf16x8*)&As[cur][(wr * 64 + mi * 16 + l16) * BK + sw];
#pragma unroll
            for (int ni = 0; ni < 2; ni++)
                b[ni] = *(const bf16x8*)&Bs[cur][(wc * 32 + ni * 16 + l16) * BK + sw];
#pragma unroll
            for (int mi = 0; mi < 4; mi++)
#pragma unroll
                for (int ni = 0; ni < 2; ni++)
                    acc[mi][ni] = __builtin_amdgcn_mfma_f32_16x16x32_bf16(a[mi], b[ni], acc[mi][ni], 0, 0, 0);
        }
        __syncthreads();
    }

    u16* outp = slot ? out1 : out0;
#pragma unroll
    for (int mi = 0; mi < 4; mi++) {
#pragma unroll
        for (int ni = 0; ni < 2; ni++) {
            int d = d0 + wc * 32 + ni * 16 + l16;
#pragma unroll
            for (int r = 0; r < 4; r++) {
                int m = wr * 64 + mi * 16 + quad * 4 + r;
                if (m0 + m < cg) {
                    outp[(size_t)tks[m] * DIM + d] = f2bf(acc[mi][ni][r]);
                }
            }
        }
    }
}

// ---------------- Combine: out = f32(o0) + f32(o1) ----------------
__global__ void combine_kernel(const u16* __restrict__ o0, const u16* __restrict__ o1,
                               float* __restrict__ out) {
    int i = blockIdx.x * blockDim.x + threadIdx.x;
    u16x8 a = *(const u16x8*)(o0 + (size_t)i * 8);
    u16x8 b = *(const u16x8*)(o1 + (size_t)i * 8);
    f32x4 r0, r1;
#pragma unroll
    for (int j = 0; j < 4; j++) {
        r0[j] = bf2f(a[j]) + bf2f(b[j]);
        r1[j] = bf2f(a[4 + j]) + bf2f(b[4 + j]);
    }
    *(f32x4*)(out + (size_t)i * 8) = r0;
    *(f32x4*)(out + (size_t)i * 8 + 4) = r1;
}

extern "C" void kernel_launch(void* const* d_in, const int* in_sizes, int n_in,
                              void* d_out, int out_size, void* d_ws, size_t ws_size,
                              hipStream_t stream) {
    const float* x  = (const float*)d_in[0];
    const float* wr = (const float*)d_in[1];
    const float* wg = (const float*)d_in[2];
    const float* wu = (const float*)d_in[3];
    const float* wd = (const float*)d_in[4];
    float* out = (float*)d_out;

    char* W = (char*)d_ws;
    int*   cnt     = (int*)(W + 0);
    int*   poscnt  = (int*)(W + 64);
    int*   base    = (int*)(W + 128);
    int*   ntiles  = (int*)(W + 192);
    int*   tile_g  = (int*)(W + 256);           // <=48
    int*   tile_m0 = (int*)(W + 512);           // <=48
    int*   rt_e    = (int*)(W + 1024);          // 4096 ints
    float* rt_p    = (float*)(W + 20480);
    int*   rowtok  = (int*)(W + 40960);
    float* rowprob = (float*)(W + 61440);
    u16*   hidden  = (u16*)(W + 81920);         // (4096+128) x 768 bf16 ~ 6.49 MB
    u16*   xb      = (u16*)(W + ((size_t)8  << 20));   // 8.39 MB
    u16*   wgb     = (u16*)(W + ((size_t)17 << 20));   // 25.2 MB (dead after gateup)
    u16*   wub     = (u16*)(W + ((size_t)43 << 20));   // 25.2 MB (dead after gateup)
    u16*   wdb     = (u16*)(W + ((size_t)69 << 20));   // 25.2 MB  (end ~94.4 MB)
    // out0/out1 overlap the wgb region (only written by down, after gateup finished)
    u16*   out0    = (u16*)(W + ((size_t)17 << 20));   // 8.39 MB
    u16*   out1    = (u16*)(W + ((size_t)26 << 20));   // 8.39 MB

    hipMemsetAsync(W, 0, 256, stream);   // cnt, poscnt, base, ntiles

    const int NW = NEXP * FF * DIM / 4;
    cvt3_kernel<<<dim3(1536, 3), 256, 0, stream>>>(wg, wgb, wu, wub, wd, wdb, NW);

    router_kernel<<<T_TOK / 4, 256, 0, stream>>>(x, wr, cnt, rt_e, rt_p, xb);
    scan_kernel<<<1, 64, 0, stream>>>(cnt, base, tile_g, tile_m0, ntiles);
    assign_kernel<<<8, 256, 0, stream>>>(rt_e, rt_p, base, poscnt, rowtok, rowprob);

    gateup_kernel<<<dim3(48, 24), 256, 0, stream>>>(xb, wgb, wub, cnt, base, tile_g, tile_m0,
                                                    ntiles, rowtok, rowprob, hidden);
    down_kernel<<<dim3(48, 32), 256, 0, stream>>>(hidden, wdb, cnt, base, tile_g, tile_m0,
                                                  ntiles, rowtok, out0, out1);
    combine_kernel<<<T_TOK * DIM / (256 * 8), 256, 0, stream>>>(out0, out1, out);
}

// Round 2
// 362.537 us; speedup vs baseline: 1.0609x; 1.0197x over previous
//
#include <hip/hip_runtime.h>

#define T_TOK 2048
#define DIM   2048
#define NEXP  8
#define FF    768
#define NGRP  16   // (expert, slot)
#define BK    64

typedef unsigned short u16;
typedef unsigned int   u32;
typedef __bf16 bf16x8 __attribute__((ext_vector_type(8)));
typedef float  f32x4  __attribute__((ext_vector_type(4)));
typedef u16    u16x4  __attribute__((ext_vector_type(4)));
typedef u16    u16x8  __attribute__((ext_vector_type(8)));

#define AS1 __attribute__((address_space(1)))
#define AS3 __attribute__((address_space(3)))

__device__ __forceinline__ u16 f2bf(float f) {
    union { u32 i; float f; } v; v.f = f;
    u32 r = v.i + 0x7FFF + ((v.i >> 16) & 1);   // round-to-nearest-even
    return (u16)(r >> 16);
}
__device__ __forceinline__ float bf2f(u16 u) {
    union { u32 i; float f; } v; v.i = ((u32)u) << 16; return v.f;
}

// async global->LDS, 16B per lane; LDS dest = wave-uniform base + lane*16
__device__ __forceinline__ void gload16(const u16* g, u16* l) {
    __builtin_amdgcn_global_load_lds((const AS1 u32*)g, (AS3 u32*)l, 16, 0, 0);
}

// ---- Fused: router (blockIdx.y==0, first-dispatched) + fp32->bf16 weight convert ----
__global__ void cvtrouter_kernel(const float* __restrict__ x, const float* __restrict__ wr,
                                 int* cnt, int* rt_e, float* rt_p, u16* __restrict__ xb,
                                 const float* __restrict__ wg, u16* __restrict__ wgb,
                                 const float* __restrict__ wu, u16* __restrict__ wub,
                                 const float* __restrict__ wd, u16* __restrict__ wdb, int n4) {
    if (blockIdx.y == 0) {
        if (blockIdx.x >= T_TOK / 4) return;
        int wave = threadIdx.x >> 6, lane = threadIdx.x & 63;
        int t = blockIdx.x * 4 + wave;
        float xv[32];
#pragma unroll
        for (int i = 0; i < 32; i++) xv[i] = x[(size_t)t * DIM + i * 64 + lane];
#pragma unroll
        for (int i = 0; i < 32; i++) xb[(size_t)t * DIM + i * 64 + lane] = f2bf(xv[i]);
        float s[NEXP];
#pragma unroll
        for (int e = 0; e < NEXP; e++) {
            float acc = 0.f;
#pragma unroll
            for (int i = 0; i < 32; i++) acc += xv[i] * wr[(size_t)e * DIM + i * 64 + lane];
            for (int off = 32; off; off >>= 1) acc += __shfl_xor(acc, off);
            s[e] = acc;
        }
        if (lane == 0) {
            int bi = 0; float bv = s[0];
            for (int e = 1; e < NEXP; e++) if (s[e] > bv) { bv = s[e]; bi = e; }
            float sv = -1e30f; int si = 0;
            for (int e = 0; e < NEXP; e++) { if (e == bi) continue; if (s[e] > sv) { sv = s[e]; si = e; } }
            float p0 = 1.f / (1.f + __expf(sv - bv));
            float p1 = 1.f - p0;
            rt_e[t * 2 + 0] = bi; rt_e[t * 2 + 1] = si;
            rt_p[t * 2 + 0] = p0; rt_p[t * 2 + 1] = p1;
            atomicAdd(&cnt[bi * 2 + 0], 1);
            atomicAdd(&cnt[si * 2 + 1], 1);
        }
        return;
    }
    const float* s; u16* d;
    switch (blockIdx.y) {
        case 1: s = wg; d = wgb; break;
        case 2: s = wu; d = wub; break;
        default: s = wd; d = wdb; break;
    }
    int i = blockIdx.x * blockDim.x + threadIdx.x;
    int st = gridDim.x * blockDim.x;
    for (; i < n4; i += st) {
        f32x4 v = ((const f32x4*)s)[i];
        u16x4 o;
#pragma unroll
        for (int j = 0; j < 4; j++) o[j] = f2bf(v[j]);
        ((u16x4*)d)[i] = o;
    }
}

// ---- Fused scan + assign: one block. Wave 0 scans; all waves then assign rows. ----
__global__ void scanassign_kernel(const int* cnt, const int* rt_e, const float* rt_p,
                                  int* base_g, int* tile_g, int* tile_m0, int* ntiles,
                                  int* rowtok, float* rowprob) {
    __shared__ int s_base[NGRP];
    __shared__ int s_pos[NGRP];
    int tid = threadIdx.x;
    if (tid < NGRP) s_pos[tid] = 0;
    if (tid < 64) {
        int lane = tid;
        int c = (lane < NGRP) ? cnt[lane] : 0;
        int nt_g = (c + 127) >> 7;
        int pre = 0, tpre = 0;
        for (int i = 0; i < NGRP; i++) {
            int ci = __shfl(c, i), ti = __shfl(nt_g, i);
            if (i < lane) { pre += ci; tpre += ti; }
        }
        if (lane < NGRP) {
            s_base[lane] = pre; base_g[lane] = pre;
            for (int j = 0; j < nt_g; j++) { tile_g[tpre + j] = lane; tile_m0[tpre + j] = j * 128; }
            if (lane == NGRP - 1) *ntiles = tpre + nt_g;
        }
    }
    __syncthreads();
    for (int t = tid; t < T_TOK; t += 256) {
#pragma unroll
        for (int k = 0; k < 2; k++) {
            int g = rt_e[t * 2 + k] * 2 + k;
            int pos = atomicAdd(&s_pos[g], 1);
            int row = s_base[g] + pos;
            rowtok[row] = t;
            rowprob[row] = rt_p[t * 2 + k];
        }
    }
}

// ---- Gate/Up GEMM + SiLU: 128 rows x 64 f (128 out-cols, gate|up interleaved) ----
// Per-wave 64x64 tile: 4x4 frags, 16 MFMA per ks fed by 8 ds_read_b128.
// BK=64, double-buffered LDS, XOR chunk-swizzle (linear gload16 dest +
// inverse-swizzled global source + swizzled ds_read).
__launch_bounds__(256)
__global__ void gateup_kernel(const u16* __restrict__ xb, const u16* __restrict__ wgb,
                              const u16* __restrict__ wub,
                              const int* cnt, const int* base, const int* tile_g,
                              const int* tile_m0, const int* ntiles,
                              const int* rowtok, const float* rowprob,
                              u16* __restrict__ hidden) {
    int tile = blockIdx.x;
    if (tile >= *ntiles) return;
    int g = tile_g[tile], m0 = tile_m0[tile];
    int e = g >> 1;
    int f0 = blockIdx.y * 64;
    int cg = cnt[g], bg_ = base[g];

    __shared__ u16 As[2][128 * BK];   // 2 x 16 KB
    __shared__ u16 Bs[2][128 * BK];   // 2 x 16 KB
    __shared__ int   tks[128];
    __shared__ float ps[128];

    int tid = threadIdx.x;
    if (tid < 128) {
        int valid = (m0 + tid) < cg;
        tks[tid] = valid ? rowtok[bg_ + m0 + tid] : 0;
        ps[tid]  = valid ? rowprob[bg_ + m0 + tid] : 0.f;
    }
    __syncthreads();

    int wave = tid >> 6, lane = tid & 63;
    int quad = lane >> 4, l16 = lane & 15;
    int wr = wave >> 1, wc = wave & 1;

    // staging: 8 rows x 8 chunks of 16B per gload16 group
    int r8  = lane >> 3;                  // row within 8-row group
    int csw = ((lane & 7) ^ r8) * 8;      // inverse-swizzled global chunk (elements)

    // A: wave stages rows [wave*32, +32) in 4 groups of 8
    const u16* gA[4]; int lA[4];
#pragma unroll
    for (int gi = 0; gi < 4; gi++) {
        int row = wave * 32 + gi * 8 + r8;
        gA[gi] = xb + (size_t)tks[row] * DIM + csw;
        lA[gi] = (wave * 32 + gi * 8) * BK;
    }
    // B LDS rows n in [0,128): type=(n>>4)&1 (0=gate,1=up), f = f0 + (n>>5)*16 + (n&15)
    // staging group (gi,wave): rows gi*32 + wave*8 + r8
    const u16* bsrc = (wave >> 1) ? wub : wgb;
    int fo = (wave & 1) * 8 + r8;
    const u16* gB[4]; int lB[4];
#pragma unroll
    for (int gi = 0; gi < 4; gi++) {
        gB[gi] = bsrc + ((size_t)e * FF + f0 + gi * 16 + fo) * DIM + csw;
        lB[gi] = (gi * 32 + wave * 8) * BK;
    }

    f32x4 acc[4][4] = {};

    // prologue: stage buffer 0
#pragma unroll
    for (int gi = 0; gi < 4; gi++) gload16(gA[gi], &As[0][0] + lA[gi]);
#pragma unroll
    for (int gi = 0; gi < 4; gi++) gload16(gB[gi], &Bs[0][0] + lB[gi]);
    __syncthreads();

    int sw0 = ((0 * 4 + quad) ^ (l16 & 7)) * 8;
    int sw1 = ((1 * 4 + quad) ^ (l16 & 7)) * 8;

#pragma unroll 2
    for (int kt = 0; kt < DIM / BK; kt++) {
        int cur = kt & 1;
        int kk = (kt + 1) * BK;
        if (kk < DIM) {
#pragma unroll
            for (int gi = 0; gi < 4; gi++) gload16(gA[gi] + kk, &As[cur ^ 1][0] + lA[gi]);
#pragma unroll
            for (int gi = 0; gi < 4; gi++) gload16(gB[gi] + kk, &Bs[cur ^ 1][0] + lB[gi]);
        }
#pragma unroll
        for (int ks = 0; ks < 2; ks++) {
            int sw = ks ? sw1 : sw0;
            bf16x8 a[4], b[4];
#pragma unroll
            for (int mi = 0; mi < 4; mi++)
                a[mi] = *(const bf16x8*)&As[cur][(wr * 64 + mi * 16 + l16) * BK + sw];
#pragma unroll
            for (int ni = 0; ni < 4; ni++)
                b[ni] = *(const bf16x8*)&Bs[cur][(wc * 64 + ni * 16 + l16) * BK + sw];
#pragma unroll
            for (int mi = 0; mi < 4; mi++)
#pragma unroll
                for (int ni = 0; ni < 4; ni++)
                    acc[mi][ni] = __builtin_amdgcn_mfma_f32_16x16x32_bf16(a[mi], b[ni], acc[mi][ni], 0, 0, 0);
        }
        __syncthreads();
    }

    // epilogue: frag k: even=gate, odd=up; f = f0 + wc*32 + (k>>1)*16 + l16
    int fb = f0 + wc * 32 + l16;
#pragma unroll
    for (int mi = 0; mi < 4; mi++) {
#pragma unroll
        for (int r = 0; r < 4; r++) {
            int m = wr * 64 + mi * 16 + quad * 4 + r;
            if (m0 + m < cg) {
                float p = ps[m];
                float g0 = acc[mi][0][r], u0 = acc[mi][1][r];
                float g1 = acc[mi][2][r], u1 = acc[mi][3][r];
                size_t rowo = (size_t)(bg_ + m0 + m) * FF;
                hidden[rowo + fb]      = f2bf((g0 / (1.f + __expf(-g0))) * u0 * p);
                hidden[rowo + fb + 16] = f2bf((g1 / (1.f + __expf(-g1))) * u1 * p);
            }
        }
    }
}

// ---- Down GEMM: 128 rows x 128 d, per-wave 64x64 (4x4 frags), BK=64, dbuf, swizzled ----
__launch_bounds__(256)
__global__ void down_kernel(const u16* __restrict__ hid, const u16* __restrict__ wdb,
                            const int* cnt, const int* base, const int* tile_g,
                            const int* tile_m0, const int* ntiles, const int* rowtok,
                            u16* __restrict__ out0, u16* __restrict__ out1) {
    int tile = blockIdx.x;
    if (tile >= *ntiles) return;
    int g = tile_g[tile], m0 = tile_m0[tile];
    int e = g >> 1, slot = g & 1;
    int d0 = blockIdx.y * 128;
    int cg = cnt[g], bg_ = base[g];

    __shared__ u16 As[2][128 * BK];
    __shared__ u16 Bs[2][128 * BK];
    __shared__ int tks[128];

    int tid = threadIdx.x;
    if (tid < 128) tks[tid] = ((m0 + tid) < cg) ? rowtok[bg_ + m0 + tid] : 0;
    __syncthreads();

    int wave = tid >> 6, lane = tid & 63;
    int quad = lane >> 4, l16 = lane & 15;
    int wr = wave >> 1, wc = wave & 1;

    int r8  = lane >> 3;
    int csw = ((lane & 7) ^ r8) * 8;

    const u16* gA[4]; int lA[4];
#pragma unroll
    for (int gi = 0; gi < 4; gi++) {
        int row = wave * 32 + gi * 8 + r8;
        gA[gi] = hid + (size_t)(bg_ + m0 + row) * FF + csw;
        lA[gi] = (wave * 32 + gi * 8) * BK;
    }
    // B LDS row n in [0,128): d = d0 + n; staging rows gi*32 + wave*8 + r8
    const u16* gB[4]; int lB[4];
#pragma unroll
    for (int gi = 0; gi < 4; gi++) {
        int n = gi * 32 + wave * 8 + r8;
        gB[gi] = wdb + ((size_t)e * DIM + d0 + n) * FF + csw;
        lB[gi] = (gi * 32 + wave * 8) * BK;
    }

    f32x4 acc[4][4] = {};

#pragma unroll
    for (int gi = 0; gi < 4; gi++) gload16(gA[gi], &As[0][0] + lA[gi]);
#pragma unroll
    for (int gi = 0; gi < 4; gi++) gload16(gB[gi], &Bs[0][0] + lB[gi]);
    __syncthreads();

    int sw0 = ((0 * 4 + quad) ^ (l16 & 7)) * 8;
    int sw1 = ((1 * 4 + quad) ^ (l16 & 7)) * 8;

#pragma unroll 2
    for (int kt = 0; kt < FF / BK; kt++) {
        int cur = kt & 1;
        int kk = (kt + 1) * BK;
        if (kk < FF) {
#pragma unroll
            for (int gi = 0; gi < 4; gi++) gload16(gA[gi] + kk, &As[cur ^ 1][0] + lA[gi]);
#pragma unroll
            for (int gi = 0; gi < 4; gi++) gload16(gB[gi] + kk, &Bs[cur ^ 1][0] + lB[gi]);
        }
#pragma unroll
        for (int ks = 0; ks < 2; ks++) {
            int sw = ks ? sw1 : sw0;
            bf16x8 a[4], b[4];
#pragma unroll
            for (int mi = 0; mi < 4; mi++)
                a[mi] = *(const bf16x8*)&As[cur][(wr * 64 + mi * 16 + l16) * BK + sw];
#pragma unroll
            for (int ni = 0; ni < 4; ni++)
                b[ni] = *(const bf16x8*)&Bs[cur][(wc * 64 + ni * 16 + l16) * BK + sw];
#pragma unroll
            for (int mi = 0; mi < 4; mi++)
#pragma unroll
                for (int ni = 0; ni < 4; ni++)
                    acc[mi][ni] = __builtin_amdgcn_mfma_f32_16x16x32_bf16(a[mi], b[ni], acc[mi][ni], 0, 0, 0);
        }
        __syncthreads();
    }

    u16* outp = slot ? out1 : out0;
#pragma unroll
    for (int mi = 0; mi < 4; mi++) {
#pragma unroll
        for (int ni = 0; ni < 4; ni++) {
            int d = d0 + wc * 64 + ni * 16 + l16;
#pragma unroll
            for (int r = 0; r < 4; r++) {
                int m = wr * 64 + mi * 16 + quad * 4 + r;
                if (m0 + m < cg) {
                    outp[(size_t)tks[m] * DIM + d] = f2bf(acc[mi][ni][r]);
                }
            }
        }
    }
}

// ---------------- Combine: out = f32(o0) + f32(o1) ----------------
__global__ void combine_kernel(const u16* __restrict__ o0, const u16* __restrict__ o1,
                               float* __restrict__ out) {
    int i = blockIdx.x * blockDim.x + threadIdx.x;
    u16x8 a = *(const u16x8*)(o0 + (size_t)i * 8);
    u16x8 b = *(const u16x8*)(o1 + (size_t)i * 8);
    f32x4 r0, r1;
#pragma unroll
    for (int j = 0; j < 4; j++) {
        r0[j] = bf2f(a[j]) + bf2f(b[j]);
        r1[j] = bf2f(a[4 + j]) + bf2f(b[4 + j]);
    }
    *(f32x4*)(out + (size_t)i * 8) = r0;
    *(f32x4*)(out + (size_t)i * 8 + 4) = r1;
}

extern "C" void kernel_launch(void* const* d_in, const int* in_sizes, int n_in,
                              void* d_out, int out_size, void* d_ws, size_t ws_size,
                              hipStream_t stream) {
    const float* x  = (const float*)d_in[0];
    const float* wr = (const float*)d_in[1];
    const float* wg = (const float*)d_in[2];
    const float* wu = (const float*)d_in[3];
    const float* wd = (const float*)d_in[4];
    float* out = (float*)d_out;

    char* W = (char*)d_ws;
    int*   cnt     = (int*)(W + 0);
    int*   base    = (int*)(W + 128);
    int*   ntiles  = (int*)(W + 192);
    int*   tile_g  = (int*)(W + 256);           // <=48
    int*   tile_m0 = (int*)(W + 512);           // <=48
    int*   rt_e    = (int*)(W + 1024);          // 4096 ints
    float* rt_p    = (float*)(W + 20480);
    int*   rowtok  = (int*)(W + 40960);
    float* rowprob = (float*)(W + 61440);
    u16*   hidden  = (u16*)(W + 81920);         // (4096+128) x 768 bf16 ~ 6.49 MB
    u16*   xb      = (u16*)(W + ((size_t)8  << 20));   // 8.39 MB
    u16*   wgb     = (u16*)(W + ((size_t)17 << 20));   // 25.2 MB (dead after gateup)
    u16*   wub     = (u16*)(W + ((size_t)43 << 20));   // 25.2 MB (dead after gateup)
    u16*   wdb     = (u16*)(W + ((size_t)69 << 20));   // 25.2 MB  (end ~94.4 MB)
    // out0/out1 overlap the wgb region (only written by down, after gateup finished)
    u16*   out0    = (u16*)(W + ((size_t)17 << 20));   // 8.39 MB
    u16*   out1    = (u16*)(W + ((size_t)26 << 20));   // 8.39 MB

    hipMemsetAsync(W, 0, 256, stream);   // cnt, base, ntiles

    const int NW = NEXP * FF * DIM / 4;
    cvtrouter_kernel<<<dim3(1536, 4), 256, 0, stream>>>(x, wr, cnt, rt_e, rt_p, xb,
                                                        wg, wgb, wu, wub, wd, wdb, NW);
    scanassign_kernel<<<1, 256, 0, stream>>>(cnt, rt_e, rt_p, base, tile_g, tile_m0,
                                             ntiles, rowtok, rowprob);

    gateup_kernel<<<dim3(48, 12), 256, 0, stream>>>(xb, wgb, wub, cnt, base, tile_g, tile_m0,
                                                    ntiles, rowtok, rowprob, hidden);
    down_kernel<<<dim3(48, 16), 256, 0, stream>>>(hidden, wdb, cnt, base, tile_g, tile_m0,
                                                  ntiles, rowtok, out0, out1);
    combine_kernel<<<T_TOK * DIM / (256 * 8), 256, 0, stream>>>(out0, out1, out);
}